// Round 4
// baseline (205.844 us; speedup 1.0000x reference)
//
#include <hip/hip_runtime.h>

// Shapes (fixed by setup_inputs): x [T=4, B=16, C=512, N=1024] fp32
// out [T,B,C,1] = [64, 512] fp32
#define T_  4
#define B_  16
#define C_  512
#define N_  1024
#define CR_ 64

static constexpr float BN_EPS = 1e-5f;

typedef float f4_t __attribute__((ext_vector_type(4)));  // native vec for nontemporal builtin

// ---------------------------------------------------------------------------
// K1: LIF 4-step recurrence + global-average-pool over N.
// One block per (b, c-pair): 256 threads x float4 x 2 channels.
// 8 independent 16B loads in flight per thread (vs 4) for latency hiding;
// 4096 blocks instead of 8192 halves launch/drain overhead.
// v <- (v + x_t) * 0.5 ; s = (v >= 1) ; v = s ? 0 : v   [hard reset]
// Lane-sum of {0,1} spikes via ballot+popcount (scalar pipe, no LDS).
// g[(t*B + b)*C + c] = count / N
// ---------------------------------------------------------------------------
__global__ __launch_bounds__(256) void lif_gap_kernel(
    const float* __restrict__ x, float* __restrict__ g) {
    const int blk = blockIdx.x;          // b*(C/2) + cc
    const int b   = blk >> 8;            // / 256
    const int c0  = (blk & 255) << 1;    // channel pair base
    const int tid = threadIdx.x;
    const size_t plane = (size_t)B_ * C_ * N_;
    const float* __restrict__ xp = x + ((size_t)(b * C_ + c0)) * N_ + (size_t)tid * 4;

    f4_t v0 = (f4_t)(0.f);
    f4_t v1 = (f4_t)(0.f);
    int cnt[T_][2];
#pragma unroll
    for (int t = 0; t < T_; ++t) {
        const f4_t xa = __builtin_nontemporal_load((const f4_t*)(xp + (size_t)t * plane));
        const f4_t xb = __builtin_nontemporal_load((const f4_t*)(xp + (size_t)t * plane + N_));
        v0.x = 0.5f * (v0.x + xa.x);  v0.y = 0.5f * (v0.y + xa.y);
        v0.z = 0.5f * (v0.z + xa.z);  v0.w = 0.5f * (v0.w + xa.w);
        v1.x = 0.5f * (v1.x + xb.x);  v1.y = 0.5f * (v1.y + xb.y);
        v1.z = 0.5f * (v1.z + xb.z);  v1.w = 0.5f * (v1.w + xb.w);
        cnt[t][0] = (int)(__popcll(__ballot(v0.x >= 1.0f)) + __popcll(__ballot(v0.y >= 1.0f)) +
                          __popcll(__ballot(v0.z >= 1.0f)) + __popcll(__ballot(v0.w >= 1.0f)));
        cnt[t][1] = (int)(__popcll(__ballot(v1.x >= 1.0f)) + __popcll(__ballot(v1.y >= 1.0f)) +
                          __popcll(__ballot(v1.z >= 1.0f)) + __popcll(__ballot(v1.w >= 1.0f)));
        v0.x = (v0.x >= 1.0f) ? 0.f : v0.x;  v0.y = (v0.y >= 1.0f) ? 0.f : v0.y;
        v0.z = (v0.z >= 1.0f) ? 0.f : v0.z;  v0.w = (v0.w >= 1.0f) ? 0.f : v0.w;
        v1.x = (v1.x >= 1.0f) ? 0.f : v1.x;  v1.y = (v1.y >= 1.0f) ? 0.f : v1.y;
        v1.z = (v1.z >= 1.0f) ? 0.f : v1.z;  v1.w = (v1.w >= 1.0f) ? 0.f : v1.w;
    }

    __shared__ int lds[4][T_][2];        // [wave][t][ch]
    const int wave = tid >> 6;
    const int lane = tid & 63;
    if (lane == 0) {
#pragma unroll
        for (int t = 0; t < T_; ++t) {
            lds[wave][t][0] = cnt[t][0];
            lds[wave][t][1] = cnt[t][1];
        }
    }
    __syncthreads();
    if (tid < T_ * 2) {                  // thread -> (t, ch)
        const int t  = tid >> 1;
        const int ch = tid & 1;
        const int tot = lds[0][t][ch] + lds[1][t][ch] + lds[2][t][ch] + lds[3][t][ch];
        g[((size_t)(t * B_ + b)) * C_ + (c0 + ch)] = (float)tot * (1.0f / N_);
    }
}

// ---------------------------------------------------------------------------
// K2: h1 = BN1(g @ w1^T + b1), h1 is [64 rows (TB), 64 cols (Cr)].
// One block per output column j (Cr). 4 waves; wave w computes rows w,w+4,...
// via length-512 dot with wave butterfly reduce. Then wave 0 does the
// batch-dim (64-row) mean/var and writes BN'd column.
// ---------------------------------------------------------------------------
__global__ __launch_bounds__(256) void fc1_bn_kernel(
    const float* __restrict__ g,  const float* __restrict__ w1,
    const float* __restrict__ b1, const float* __restrict__ gamma1,
    const float* __restrict__ beta1, float* __restrict__ h1) {
    const int j    = blockIdx.x;         // 0..63
    const int tid  = threadIdx.x;
    const int lane = tid & 63;
    const int wave = tid >> 6;
    __shared__ float rowval[64];

    const float* __restrict__ w1r = w1 + (size_t)j * C_;
    for (int i = wave; i < 64; i += 4) {
        float p = 0.f;
        const float* __restrict__ gr = g + (size_t)i * C_;
#pragma unroll
        for (int m = 0; m < C_ / 64; ++m) {
            const int k = lane + 64 * m;
            p += gr[k] * w1r[k];
        }
#pragma unroll
        for (int off = 32; off >= 1; off >>= 1) p += __shfl_xor(p, off, 64);
        if (lane == 0) rowval[i] = p + b1[j];
    }
    __syncthreads();
    if (tid < 64) {                      // exactly wave 0 (wavefront = 64)
        const float v = rowval[tid];
        float s  = v;
        float s2 = v * v;
#pragma unroll
        for (int off = 32; off >= 1; off >>= 1) {
            s  += __shfl_xor(s,  off, 64);
            s2 += __shfl_xor(s2, off, 64);
        }
        const float mu  = s * (1.f / 64.f);
        const float var = s2 * (1.f / 64.f) - mu * mu;
        h1[(size_t)tid * CR_ + j] =
            (v - mu) * rsqrtf(var + BN_EPS) * gamma1[j] + beta1[j];
    }
}

// ---------------------------------------------------------------------------
// K3: out = BN2(h1 @ w2^T + b2), out is [64 rows (TB), 512 cols (C)].
// One block (= one wave) per output column j; lane = row. Dot of length 64,
// then butterfly mean/var across the 64 rows held one-per-lane.
// ---------------------------------------------------------------------------
__global__ __launch_bounds__(64) void fc2_bn_kernel(
    const float* __restrict__ h1, const float* __restrict__ w2,
    const float* __restrict__ b2, const float* __restrict__ gamma2,
    const float* __restrict__ beta2, float* __restrict__ out) {
    const int j = blockIdx.x;            // 0..511
    const int i = threadIdx.x;           // row 0..63
    const float* __restrict__ w2r = w2 + (size_t)j * CR_;
    const float* __restrict__ hr  = h1 + (size_t)i * CR_;
    float v = b2[j];
#pragma unroll
    for (int k = 0; k < CR_; ++k) v += hr[k] * w2r[k];

    float s  = v;
    float s2 = v * v;
#pragma unroll
    for (int off = 32; off >= 1; off >>= 1) {
        s  += __shfl_xor(s,  off, 64);
        s2 += __shfl_xor(s2, off, 64);
    }
    const float mu  = s * (1.f / 64.f);
    const float var = s2 * (1.f / 64.f) - mu * mu;
    out[(size_t)i * C_ + j] =
        (v - mu) * rsqrtf(var + BN_EPS) * gamma2[j] + beta2[j];
}

extern "C" void kernel_launch(void* const* d_in, const int* in_sizes, int n_in,
                              void* d_out, int out_size, void* d_ws, size_t ws_size,
                              hipStream_t stream) {
    const float* x      = (const float*)d_in[0];
    const float* w1     = (const float*)d_in[1];
    const float* b1     = (const float*)d_in[2];
    const float* gamma1 = (const float*)d_in[3];
    const float* beta1  = (const float*)d_in[4];
    const float* w2     = (const float*)d_in[5];
    const float* b2     = (const float*)d_in[6];
    const float* gamma2 = (const float*)d_in[7];
    const float* beta2  = (const float*)d_in[8];
    float* out = (float*)d_out;

    float* g  = (float*)d_ws;            // [64, 512]  = 128 KiB
    float* h1 = g + 64 * C_;             // [64, 64]   =  16 KiB

    lif_gap_kernel<<<(B_ * C_) / 2, 256, 0, stream>>>(x, g);
    fc1_bn_kernel<<<CR_, 256, 0, stream>>>(g, w1, b1, gamma1, beta1, h1);
    fc2_bn_kernel<<<C_, 64, 0, stream>>>(h1, w2, b2, gamma2, beta2, out);
}